// Round 1
// baseline (1043.771 us; speedup 1.0000x reference)
//
#include <hip/hip_runtime.h>
#include <math.h>

#define D_MODEL 1024
#define RANK    64
#define PMAX    16
#define S_LEN   1024
#define HD      64
#define MROWS   4096   // B*S
#define NHEAD   16
#define BATCH   4

// ---------------------------------------------------------------------------
// Kernel 0: softmax -> top-k -> renormalize (== softmax over selected logits)
// ---------------------------------------------------------------------------
__global__ void topk_weights_kernel(const float* __restrict__ ql,
                                    const float* __restrict__ kl,
                                    const float* __restrict__ vl,
                                    const int* __restrict__ topk,
                                    int* __restrict__ idx_out,     // [3][16]
                                    float* __restrict__ w_out) {   // [3][16]
    int bank = threadIdx.x;
    if (bank >= 3) return;
    const float* lg = (bank == 0) ? ql : (bank == 1) ? kl : vl;
    int K = *topk; if (K < 1) K = 1; if (K > PMAX) K = PMAX;
    float l[PMAX];
    for (int i = 0; i < PMAX; ++i) l[i] = lg[i];
    bool used[PMAX];
    for (int i = 0; i < PMAX; ++i) used[i] = false;
    int   sel_i[PMAX];
    float sel_l[PMAX];
    for (int j = 0; j < K; ++j) {
        int best = -1; float bv = -INFINITY;
        for (int i = 0; i < PMAX; ++i)
            if (!used[i] && l[i] > bv) { bv = l[i]; best = i; }
        used[best] = true; sel_i[j] = best; sel_l[j] = bv;
    }
    float mx = sel_l[0];            // first selected is the global max
    float e[PMAX];
    float sum = 0.f;
    for (int j = 0; j < K; ++j) { e[j] = __expf(sel_l[j] - mx); sum += e[j]; }
    float inv = 1.f / sum;
    for (int j = 0; j < PMAX; ++j) {
        idx_out[bank * PMAX + j] = (j < K) ? sel_i[j] : 0;
        w_out[bank * PMAX + j]   = (j < K) ? e[j] * inv : 0.f;
    }
}

// ---------------------------------------------------------------------------
// Kernel 1: h[bank] = x @ U[idx_j]   (per (bank, j): [4096,1024]@[1024,64])
// h layout: [3][4096][1024] (col block j*64, stride fixed 1024 = kmax*64)
// ---------------------------------------------------------------------------
__global__ __launch_bounds__(256) void gemm_h_kernel(
    const float* __restrict__ x,
    const float* __restrict__ qU, const float* __restrict__ kU,
    const float* __restrict__ vU,
    const int* __restrict__ idx, const int* __restrict__ topk,
    float* __restrict__ h) {
    int bank = blockIdx.z;
    int j    = blockIdx.y;
    int K = *topk; if (K < 1) K = 1; if (K > PMAX) K = PMAX;
    if (j >= K) return;
    const float* U = (bank == 0) ? qU : (bank == 1) ? kU : vU;
    int p = idx[bank * PMAX + j];
    const float* Bm = U + (size_t)p * (D_MODEL * RANK);   // [1024][64]
    float* C = h + (size_t)bank * MROWS * D_MODEL;
    int m0 = blockIdx.x * 64;
    int t  = threadIdx.x;
    int tx = t & 15, ty = t >> 4;

    __shared__ float As[16][68];   // As[k][m]
    __shared__ float Bs[16][68];   // Bs[k][n]
    float acc[4][4];
#pragma unroll
    for (int i = 0; i < 4; ++i)
#pragma unroll
        for (int jj = 0; jj < 4; ++jj) acc[i][jj] = 0.f;

    int arow = t >> 2, akq = (t & 3) << 2;
    int bkk  = t >> 4, bc4 = (t & 15) << 2;

    for (int kt = 0; kt < D_MODEL / 16; ++kt) {
        int k0 = kt * 16;
        float4 a4 = *(const float4*)(x + (size_t)(m0 + arow) * D_MODEL + k0 + akq);
        float4 b4 = *(const float4*)(Bm + (size_t)(k0 + bkk) * RANK + bc4);
        As[akq + 0][arow] = a4.x; As[akq + 1][arow] = a4.y;
        As[akq + 2][arow] = a4.z; As[akq + 3][arow] = a4.w;
        *(float4*)&Bs[bkk][bc4] = b4;
        __syncthreads();
#pragma unroll
        for (int kk = 0; kk < 16; ++kk) {
            float4 av = *(const float4*)&As[kk][ty << 2];
            float4 bv = *(const float4*)&Bs[kk][tx << 2];
            float a_[4] = {av.x, av.y, av.z, av.w};
            float b_[4] = {bv.x, bv.y, bv.z, bv.w};
#pragma unroll
            for (int i = 0; i < 4; ++i)
#pragma unroll
                for (int jj = 0; jj < 4; ++jj) acc[i][jj] += a_[i] * b_[jj];
        }
        __syncthreads();
    }
#pragma unroll
    for (int i = 0; i < 4; ++i) {
        float4 o = make_float4(acc[i][0], acc[i][1], acc[i][2], acc[i][3]);
        *(float4*)(C + (size_t)(m0 + (ty << 2) + i) * D_MODEL + (j << 6) + (tx << 2)) = o;
    }
}

// ---------------------------------------------------------------------------
// Kernel 2: qkv[bank] = h[bank] @ (w_j * V[idx_j]) written as [B][H][S][D]
// ---------------------------------------------------------------------------
__global__ __launch_bounds__(256) void gemm_qkv_kernel(
    const float* __restrict__ h,
    const float* __restrict__ qV, const float* __restrict__ kV,
    const float* __restrict__ vV,
    const int* __restrict__ idx, const float* __restrict__ wsel,
    const int* __restrict__ topk,
    float* __restrict__ qkv) {
    int bank = blockIdx.z;
    int head = blockIdx.y;      // 0..15 -> output 64-col block
    int K = *topk; if (K < 1) K = 1; if (K > PMAX) K = PMAX;
    const float* V = (bank == 0) ? qV : (bank == 1) ? kV : vV;
    const float* A = h + (size_t)bank * MROWS * D_MODEL;
    float* outp = qkv + (size_t)bank * MROWS * D_MODEL;
    int m0 = blockIdx.x * 64;
    int t  = threadIdx.x;
    int tx = t & 15, ty = t >> 4;

    __shared__ float As[16][68];
    __shared__ float Bs[16][68];
    float acc[4][4];
#pragma unroll
    for (int i = 0; i < 4; ++i)
#pragma unroll
        for (int jj = 0; jj < 4; ++jj) acc[i][jj] = 0.f;

    int arow = t >> 2, akq = (t & 3) << 2;
    int bkk  = t >> 4, bc4 = (t & 15) << 2;

    int ktiles = K * 4;   // Kdim = K*64
    for (int kt = 0; kt < ktiles; ++kt) {
        int k0 = kt * 16;
        float4 a4 = *(const float4*)(A + (size_t)(m0 + arow) * D_MODEL + k0 + akq);
        int kkg = k0 + bkk;
        int jj  = kkg >> 6;
        int rr  = kkg & 63;
        int p   = idx[bank * PMAX + jj];
        float wj = wsel[bank * PMAX + jj];
        float4 b4 = *(const float4*)(V + ((size_t)p * RANK + rr) * D_MODEL + (head << 6) + bc4);
        b4.x *= wj; b4.y *= wj; b4.z *= wj; b4.w *= wj;
        As[akq + 0][arow] = a4.x; As[akq + 1][arow] = a4.y;
        As[akq + 2][arow] = a4.z; As[akq + 3][arow] = a4.w;
        *(float4*)&Bs[bkk][bc4] = b4;
        __syncthreads();
#pragma unroll
        for (int kk = 0; kk < 16; ++kk) {
            float4 av = *(const float4*)&As[kk][ty << 2];
            float4 bv = *(const float4*)&Bs[kk][tx << 2];
            float a_[4] = {av.x, av.y, av.z, av.w};
            float b_[4] = {bv.x, bv.y, bv.z, bv.w};
#pragma unroll
            for (int i = 0; i < 4; ++i)
#pragma unroll
                for (int q = 0; q < 4; ++q) acc[i][q] += a_[i] * b_[q];
        }
        __syncthreads();
    }
#pragma unroll
    for (int i = 0; i < 4; ++i) {
        int m = m0 + (ty << 2) + i;
        int b = m >> 10;
        int s = m & 1023;
        float4 o = make_float4(acc[i][0], acc[i][1], acc[i][2], acc[i][3]);
        *(float4*)(outp + (((size_t)(b * NHEAD + head) << 10) + s) * HD + (tx << 2)) = o;
    }
}

// ---------------------------------------------------------------------------
// Kernel 3: causal flash attention, fp32. One block = (q-tile of 64, head bh)
// thread t: q-row = t>>2, key/col segment = t&3 (16 keys / 16 cols)
// ---------------------------------------------------------------------------
__global__ __launch_bounds__(256) void attn_kernel(
    const float* __restrict__ qkv, float* __restrict__ attn_out) {
    const size_t BSTR = (size_t)MROWS * D_MODEL;   // bank stride
    int qt = blockIdx.x;          // 0..15
    int bh = blockIdx.y;          // 0..63
    const float* Qp = qkv + (size_t)bh * (S_LEN * HD);
    const float* Kp = qkv + BSTR + (size_t)bh * (S_LEN * HD);
    const float* Vp = qkv + 2 * BSTR + (size_t)bh * (S_LEN * HD);
    int t  = threadIdx.x;
    int qr = t >> 2;
    int ks = t & 3;
    int qg = qt * 64 + qr;

    float qreg[64];
    {
        const float* qrow = Qp + (size_t)qg * HD;
#pragma unroll
        for (int i = 0; i < 16; ++i) {
            float4 f = *(const float4*)(qrow + i * 4);
            qreg[i * 4 + 0] = f.x; qreg[i * 4 + 1] = f.y;
            qreg[i * 4 + 2] = f.z; qreg[i * 4 + 3] = f.w;
        }
    }

    __shared__ float Ksh[64][68];
    __shared__ float Vsh[64][64];
    __shared__ float Psh[64][65];

    float O[16];
#pragma unroll
    for (int c = 0; c < 16; ++c) O[c] = 0.f;
    float m = -INFINITY, l = 0.f;

    for (int jt = 0; jt <= qt; ++jt) {
        __syncthreads();   // protect Ksh/Vsh/Psh from previous iteration readers
#pragma unroll
        for (int i = 0; i < 4; ++i) {
            int id  = t + 256 * i;
            int row = id >> 4;
            int c4  = (id & 15) << 2;
            *(float4*)&Ksh[row][c4] = *(const float4*)(Kp + (size_t)(jt * 64 + row) * HD + c4);
            *(float4*)&Vsh[row][c4] = *(const float4*)(Vp + (size_t)(jt * 64 + row) * HD + c4);
        }
        __syncthreads();

        float s[16];
#pragma unroll
        for (int kk = 0; kk < 16; ++kk) s[kk] = 0.f;
#pragma unroll 4
        for (int d4 = 0; d4 < 16; ++d4) {
            float q0 = qreg[d4 * 4 + 0], q1 = qreg[d4 * 4 + 1];
            float q2 = qreg[d4 * 4 + 2], q3 = qreg[d4 * 4 + 3];
#pragma unroll
            for (int kk = 0; kk < 16; ++kk) {
                float4 k4 = *(const float4*)&Ksh[ks * 16 + kk][d4 << 2];
                s[kk] += q0 * k4.x + q1 * k4.y + q2 * k4.z + q3 * k4.w;
            }
        }

        int kbase = jt * 64 + ks * 16;
        float tm = -INFINITY;
#pragma unroll
        for (int kk = 0; kk < 16; ++kk) {
            float sv = s[kk] * 0.125f;             // 1/sqrt(64)
            if (kbase + kk > qg) sv = -INFINITY;   // causal mask
            s[kk] = sv;
            tm = fmaxf(tm, sv);
        }
        tm = fmaxf(tm, __shfl_xor(tm, 1));
        tm = fmaxf(tm, __shfl_xor(tm, 2));
        float mnew  = fmaxf(m, tm);
        float alpha = __expf(m - mnew);
        float psum = 0.f;
#pragma unroll
        for (int kk = 0; kk < 16; ++kk) {
            float p = __expf(s[kk] - mnew);
            s[kk] = p; psum += p;
        }
        psum += __shfl_xor(psum, 1);
        psum += __shfl_xor(psum, 2);
        l = l * alpha + psum;
        m = mnew;
#pragma unroll
        for (int c = 0; c < 16; ++c) O[c] *= alpha;
#pragma unroll
        for (int kk = 0; kk < 16; ++kk) Psh[qr][ks * 16 + kk] = s[kk];
        __syncthreads();

#pragma unroll 8
        for (int key = 0; key < 64; ++key) {
            float p = Psh[qr][key];
            float4 v0 = *(const float4*)&Vsh[key][ks * 16 + 0];
            float4 v1 = *(const float4*)&Vsh[key][ks * 16 + 4];
            float4 v2 = *(const float4*)&Vsh[key][ks * 16 + 8];
            float4 v3 = *(const float4*)&Vsh[key][ks * 16 + 12];
            O[0]  += p * v0.x; O[1]  += p * v0.y; O[2]  += p * v0.z; O[3]  += p * v0.w;
            O[4]  += p * v1.x; O[5]  += p * v1.y; O[6]  += p * v1.z; O[7]  += p * v1.w;
            O[8]  += p * v2.x; O[9]  += p * v2.y; O[10] += p * v2.z; O[11] += p * v2.w;
            O[12] += p * v3.x; O[13] += p * v3.y; O[14] += p * v3.z; O[15] += p * v3.w;
        }
    }

    float inv = 1.f / l;
    int b  = bh >> 4;
    int hh = bh & 15;
    float* orow = attn_out + ((size_t)(b * S_LEN + qg)) * D_MODEL + hh * 64 + ks * 16;
#pragma unroll
    for (int c4 = 0; c4 < 4; ++c4) {
        float4 o = make_float4(O[c4 * 4 + 0] * inv, O[c4 * 4 + 1] * inv,
                               O[c4 * 4 + 2] * inv, O[c4 * 4 + 3] * inv);
        *(float4*)(orow + c4 * 4) = o;
    }
}

// ---------------------------------------------------------------------------
// Kernel 4: out = attn @ out_w^T   ([4096,1024] @ [1024,1024]^T)
// ---------------------------------------------------------------------------
__global__ __launch_bounds__(256) void gemm_proj_kernel(
    const float* __restrict__ A, const float* __restrict__ W,
    float* __restrict__ Cout) {
    int m0 = blockIdx.x * 64;
    int n0 = blockIdx.y * 64;
    int t  = threadIdx.x;
    int tx = t & 15, ty = t >> 4;

    __shared__ float As[16][68];
    __shared__ float Bs[16][68];
    float acc[4][4];
#pragma unroll
    for (int i = 0; i < 4; ++i)
#pragma unroll
        for (int jj = 0; jj < 4; ++jj) acc[i][jj] = 0.f;

    int arow = t >> 2, akq = (t & 3) << 2;
    int bn   = t >> 2, bkq = (t & 3) << 2;

    for (int kt = 0; kt < D_MODEL / 16; ++kt) {
        int k0 = kt * 16;
        float4 a4 = *(const float4*)(A + (size_t)(m0 + arow) * D_MODEL + k0 + akq);
        float4 w4 = *(const float4*)(W + (size_t)(n0 + bn) * D_MODEL + k0 + bkq);
        As[akq + 0][arow] = a4.x; As[akq + 1][arow] = a4.y;
        As[akq + 2][arow] = a4.z; As[akq + 3][arow] = a4.w;
        Bs[bkq + 0][bn] = w4.x; Bs[bkq + 1][bn] = w4.y;   // transpose W tile
        Bs[bkq + 2][bn] = w4.z; Bs[bkq + 3][bn] = w4.w;
        __syncthreads();
#pragma unroll
        for (int kk = 0; kk < 16; ++kk) {
            float4 av = *(const float4*)&As[kk][ty << 2];
            float4 bv = *(const float4*)&Bs[kk][tx << 2];
            float a_[4] = {av.x, av.y, av.z, av.w};
            float b_[4] = {bv.x, bv.y, bv.z, bv.w};
#pragma unroll
            for (int i = 0; i < 4; ++i)
#pragma unroll
                for (int jj = 0; jj < 4; ++jj) acc[i][jj] += a_[i] * b_[jj];
        }
        __syncthreads();
    }
#pragma unroll
    for (int i = 0; i < 4; ++i) {
        float4 o = make_float4(acc[i][0], acc[i][1], acc[i][2], acc[i][3]);
        *(float4*)(Cout + (size_t)(m0 + (ty << 2) + i) * D_MODEL + n0 + (tx << 2)) = o;
    }
}

// ---------------------------------------------------------------------------
extern "C" void kernel_launch(void* const* d_in, const int* in_sizes, int n_in,
                              void* d_out, int out_size, void* d_ws, size_t ws_size,
                              hipStream_t stream) {
    const float* x    = (const float*)d_in[0];
    const float* qU   = (const float*)d_in[1];
    const float* qV   = (const float*)d_in[2];
    const float* kU   = (const float*)d_in[3];
    const float* kV   = (const float*)d_in[4];
    const float* vU   = (const float*)d_in[5];
    const float* vV   = (const float*)d_in[6];
    const float* qlg  = (const float*)d_in[7];
    const float* klg  = (const float*)d_in[8];
    const float* vlg  = (const float*)d_in[9];
    const float* outw = (const float*)d_in[10];
    const int*   topk = (const int*)d_in[11];
    float* outp = (float*)d_out;

    char* ws = (char*)d_ws;
    int*   idxp = (int*)ws;                         // [3][16] ints
    float* wp   = (float*)(ws + 256);               // [3][16] floats
    float* hbuf = (float*)(ws + 512);               // [3][4096][1024] = 48 MB
    float* qkvb = hbuf + (size_t)3 * MROWS * D_MODEL;  // [3][B][H][S][D] = 48 MB
    float* attnb = hbuf;                            // reuse h region (16 MB)

    topk_weights_kernel<<<1, 64, 0, stream>>>(qlg, klg, vlg, topk, idxp, wp);
    gemm_h_kernel<<<dim3(64, 16, 3), 256, 0, stream>>>(x, qU, kU, vU, idxp, topk, hbuf);
    gemm_qkv_kernel<<<dim3(64, 16, 3), 256, 0, stream>>>(hbuf, qV, kV, vV, idxp, wp, topk, qkvb);
    attn_kernel<<<dim3(16, 64), 256, 0, stream>>>(qkvb, attnb);
    gemm_proj_kernel<<<dim3(64, 16), 256, 0, stream>>>(attnb, outw, outp);
}

// Round 2
// 460.256 us; speedup vs baseline: 2.2678x; 2.2678x over previous
//
#include <hip/hip_runtime.h>
#include <math.h>

#define D_MODEL 1024
#define RANK    64
#define PMAX    16
#define S_LEN   1024
#define HD      64
#define MROWS   4096   // B*S
#define NHEAD   16
#define BATCH   4

typedef short short8v __attribute__((ext_vector_type(8)));
typedef float floatx4 __attribute__((ext_vector_type(4)));

// fp32 -> bf16 bits, round-to-nearest-even (finite inputs only)
static __device__ __forceinline__ short f2bf(float f) {
    unsigned int u = __float_as_uint(f);
    u = (u + 0x7fffu + ((u >> 16) & 1u)) >> 16;
    return (short)u;
}

// ---------------------------------------------------------------------------
// Kernel 0: softmax -> top-k -> renormalize (== softmax over selected logits)
// ---------------------------------------------------------------------------
__global__ void topk_weights_kernel(const float* __restrict__ ql,
                                    const float* __restrict__ kl,
                                    const float* __restrict__ vl,
                                    const int* __restrict__ topk,
                                    int* __restrict__ idx_out,     // [3][16]
                                    float* __restrict__ w_out) {   // [3][16]
    int bank = threadIdx.x;
    if (bank >= 3) return;
    const float* lg = (bank == 0) ? ql : (bank == 1) ? kl : vl;
    int K = *topk; if (K < 1) K = 1; if (K > PMAX) K = PMAX;
    float l[PMAX];
    for (int i = 0; i < PMAX; ++i) l[i] = lg[i];
    bool used[PMAX];
    for (int i = 0; i < PMAX; ++i) used[i] = false;
    int   sel_i[PMAX];
    float sel_l[PMAX];
    for (int j = 0; j < K; ++j) {
        int best = -1; float bv = -INFINITY;
        for (int i = 0; i < PMAX; ++i)
            if (!used[i] && l[i] > bv) { bv = l[i]; best = i; }
        used[best] = true; sel_i[j] = best; sel_l[j] = bv;
    }
    float mx = sel_l[0];
    float e[PMAX];
    float sum = 0.f;
    for (int j = 0; j < K; ++j) { e[j] = __expf(sel_l[j] - mx); sum += e[j]; }
    float inv = 1.f / sum;
    for (int j = 0; j < PMAX; ++j) {
        idx_out[bank * PMAX + j] = (j < K) ? sel_i[j] : 0;
        w_out[bank * PMAX + j]   = (j < K) ? e[j] * inv : 0.f;
    }
}

// ---------------------------------------------------------------------------
// Kernel 1: h[bank] = x @ U[idx_j]   (per (bank, j): [4096,1024]@[1024,64])
// ---------------------------------------------------------------------------
__global__ __launch_bounds__(256) void gemm_h_kernel(
    const float* __restrict__ x,
    const float* __restrict__ qU, const float* __restrict__ kU,
    const float* __restrict__ vU,
    const int* __restrict__ idx, const int* __restrict__ topk,
    float* __restrict__ h) {
    int bank = blockIdx.z;
    int j    = blockIdx.y;
    int K = *topk; if (K < 1) K = 1; if (K > PMAX) K = PMAX;
    if (j >= K) return;
    const float* U = (bank == 0) ? qU : (bank == 1) ? kU : vU;
    int p = idx[bank * PMAX + j];
    const float* Bm = U + (size_t)p * (D_MODEL * RANK);
    float* C = h + (size_t)bank * MROWS * D_MODEL;
    int m0 = blockIdx.x * 64;
    int t  = threadIdx.x;
    int tx = t & 15, ty = t >> 4;

    __shared__ float As[16][68];
    __shared__ float Bs[16][68];
    float acc[4][4];
#pragma unroll
    for (int i = 0; i < 4; ++i)
#pragma unroll
        for (int jj = 0; jj < 4; ++jj) acc[i][jj] = 0.f;

    int arow = t >> 2, akq = (t & 3) << 2;
    int bkk  = t >> 4, bc4 = (t & 15) << 2;

    for (int kt = 0; kt < D_MODEL / 16; ++kt) {
        int k0 = kt * 16;
        float4 a4 = *(const float4*)(x + (size_t)(m0 + arow) * D_MODEL + k0 + akq);
        float4 b4 = *(const float4*)(Bm + (size_t)(k0 + bkk) * RANK + bc4);
        As[akq + 0][arow] = a4.x; As[akq + 1][arow] = a4.y;
        As[akq + 2][arow] = a4.z; As[akq + 3][arow] = a4.w;
        *(float4*)&Bs[bkk][bc4] = b4;
        __syncthreads();
#pragma unroll
        for (int kk = 0; kk < 16; ++kk) {
            float4 av = *(const float4*)&As[kk][ty << 2];
            float4 bv = *(const float4*)&Bs[kk][tx << 2];
            float a_[4] = {av.x, av.y, av.z, av.w};
            float b_[4] = {bv.x, bv.y, bv.z, bv.w};
#pragma unroll
            for (int i = 0; i < 4; ++i)
#pragma unroll
                for (int jj = 0; jj < 4; ++jj) acc[i][jj] += a_[i] * b_[jj];
        }
        __syncthreads();
    }
#pragma unroll
    for (int i = 0; i < 4; ++i) {
        float4 o = make_float4(acc[i][0], acc[i][1], acc[i][2], acc[i][3]);
        *(float4*)(C + (size_t)(m0 + (ty << 2) + i) * D_MODEL + (j << 6) + (tx << 2)) = o;
    }
}

// ---------------------------------------------------------------------------
// Kernel 2: qkv[bank] = h[bank] @ (w_j * V[idx_j]) -> bf16, layout [B][H][S][D]
// ---------------------------------------------------------------------------
__global__ __launch_bounds__(256) void gemm_qkv_kernel(
    const float* __restrict__ h,
    const float* __restrict__ qV, const float* __restrict__ kV,
    const float* __restrict__ vV,
    const int* __restrict__ idx, const float* __restrict__ wsel,
    const int* __restrict__ topk,
    short* __restrict__ qkv) {
    int bank = blockIdx.z;
    int head = blockIdx.y;
    int K = *topk; if (K < 1) K = 1; if (K > PMAX) K = PMAX;
    const float* V = (bank == 0) ? qV : (bank == 1) ? kV : vV;
    const float* A = h + (size_t)bank * MROWS * D_MODEL;
    short* outp = qkv + (size_t)bank * MROWS * D_MODEL;
    int m0 = blockIdx.x * 64;
    int t  = threadIdx.x;
    int tx = t & 15, ty = t >> 4;

    __shared__ float As[16][68];
    __shared__ float Bs[16][68];
    float acc[4][4];
#pragma unroll
    for (int i = 0; i < 4; ++i)
#pragma unroll
        for (int jj = 0; jj < 4; ++jj) acc[i][jj] = 0.f;

    int arow = t >> 2, akq = (t & 3) << 2;
    int bkk  = t >> 4, bc4 = (t & 15) << 2;

    int ktiles = K * 4;
    for (int kt = 0; kt < ktiles; ++kt) {
        int k0 = kt * 16;
        float4 a4 = *(const float4*)(A + (size_t)(m0 + arow) * D_MODEL + k0 + akq);
        int kkg = k0 + bkk;
        int jj  = kkg >> 6;
        int rr  = kkg & 63;
        int p   = idx[bank * PMAX + jj];
        float wj = wsel[bank * PMAX + jj];
        float4 b4 = *(const float4*)(V + ((size_t)p * RANK + rr) * D_MODEL + (head << 6) + bc4);
        b4.x *= wj; b4.y *= wj; b4.z *= wj; b4.w *= wj;
        As[akq + 0][arow] = a4.x; As[akq + 1][arow] = a4.y;
        As[akq + 2][arow] = a4.z; As[akq + 3][arow] = a4.w;
        *(float4*)&Bs[bkk][bc4] = b4;
        __syncthreads();
#pragma unroll
        for (int kk = 0; kk < 16; ++kk) {
            float4 av = *(const float4*)&As[kk][ty << 2];
            float4 bv = *(const float4*)&Bs[kk][tx << 2];
            float a_[4] = {av.x, av.y, av.z, av.w};
            float b_[4] = {bv.x, bv.y, bv.z, bv.w};
#pragma unroll
            for (int i = 0; i < 4; ++i)
#pragma unroll
                for (int q = 0; q < 4; ++q) acc[i][q] += a_[i] * b_[q];
        }
        __syncthreads();
    }
#pragma unroll
    for (int i = 0; i < 4; ++i) {
        int m = m0 + (ty << 2) + i;
        int b = m >> 10;
        int s = m & 1023;
        short4 o4;
        o4.x = f2bf(acc[i][0]); o4.y = f2bf(acc[i][1]);
        o4.z = f2bf(acc[i][2]); o4.w = f2bf(acc[i][3]);
        *(short4*)(outp + (((size_t)(b * NHEAD + head) << 10) + s) * HD + (tx << 2)) = o4;
    }
}

// ---------------------------------------------------------------------------
// Kernel 3: causal flash attention, bf16 MFMA (16x16x32).
// Block = 256 thr (4 waves). blockIdx.x = pair pr (0..7): processes q-tiles
// {pr, 15-pr} -> exactly 17 K-tile iterations per block (perfect balance).
// Wave w owns 16 q-rows of the 64-row q-tile.
// ---------------------------------------------------------------------------
__global__ __launch_bounds__(256) void attn_mfma_kernel(
    const short* __restrict__ qkv,    // bf16 bits [3][BH=64][S=1024][D=64]
    float* __restrict__ attn_out) {   // [B=4][S=1024][H*D=1024] fp32
    const int t    = threadIdx.x;
    const int w    = t >> 6;
    const int lane = t & 63;
    const int col  = lane & 15;
    const int quad = lane >> 4;
    const int pr   = blockIdx.x;   // 0..7
    const int bh   = blockIdx.y;   // 0..63
    const size_t HS   = (size_t)S_LEN * HD;
    const size_t BSTR = (size_t)MROWS * D_MODEL;
    const short* Qg = qkv + (size_t)bh * HS;
    const short* Kg = qkv + BSTR + (size_t)bh * HS;
    const short* Vg = qkv + 2 * BSTR + (size_t)bh * HS;

    __shared__ short Ks[64][72];      // [key][d]
    __shared__ short Vt[64][72];      // [d][key] (transposed)
    __shared__ short Ps[4][16][72];   // per-wave P [q][key]

    const float SC = 0.125f * 1.44269504f;   // 1/sqrt(64) * log2(e)

    for (int ph = 0; ph < 2; ++ph) {
        const int qt = ph ? (15 - pr) : pr;
        const int qrow = qt * 64 + w * 16 + col;
        short8v aq0 = *(const short8v*)(Qg + (size_t)qrow * HD + quad * 8);
        short8v aq1 = *(const short8v*)(Qg + (size_t)qrow * HD + 32 + quad * 8);
        floatx4 O0 = {0.f, 0.f, 0.f, 0.f}, O1 = O0, O2 = O0, O3 = O0;
        float mrow[4] = {-INFINITY, -INFINITY, -INFINITY, -INFINITY};
        float lrow[4] = {0.f, 0.f, 0.f, 0.f};

        for (int jt = 0; jt <= qt; ++jt) {
            __syncthreads();   // protect K/V tiles from prior-iter readers
            // ---- stage K tile (row-major) ----
            {
                int c = t;
                int key = c >> 3, db = (c & 7) * 8;
                *(short8v*)&Ks[key][db] =
                    *(const short8v*)(Kg + (size_t)(jt * 64 + key) * HD + db);
                c = t + 256;
                key = c >> 3; db = (c & 7) * 8;
                *(short8v*)&Ks[key][db] =
                    *(const short8v*)(Kg + (size_t)(jt * 64 + key) * HD + db);
            }
            // ---- stage V tile transposed (packed pair writes) ----
            {
                int k0 = (t & 31) * 2;
                int db = (t >> 5) * 8;
                short8v v0 = *(const short8v*)(Vg + (size_t)(jt * 64 + k0) * HD + db);
                short8v v1 = *(const short8v*)(Vg + (size_t)(jt * 64 + k0 + 1) * HD + db);
#pragma unroll
                for (int i = 0; i < 8; ++i) {
                    unsigned int pk = (unsigned int)(unsigned short)v0[i] |
                                      ((unsigned int)(unsigned short)v1[i] << 16);
                    *(unsigned int*)&Vt[db + i][k0] = pk;
                }
            }
            __syncthreads();

            const bool diag = (jt == qt);
            const int  nmax = diag ? w : 3;
            float sc[4][4];
#pragma unroll
            for (int n = 0; n < 4; ++n) {
                if (n <= nmax) {
                    floatx4 c4 = {0.f, 0.f, 0.f, 0.f};
                    short8v b0 = *(const short8v*)&Ks[n * 16 + col][quad * 8];
                    short8v b1 = *(const short8v*)&Ks[n * 16 + col][32 + quad * 8];
                    c4 = __builtin_amdgcn_mfma_f32_16x16x32_bf16(aq0, b0, c4, 0, 0, 0);
                    c4 = __builtin_amdgcn_mfma_f32_16x16x32_bf16(aq1, b1, c4, 0, 0, 0);
#pragma unroll
                    for (int r = 0; r < 4; ++r) {
                        float v = c4[r] * SC;
                        if (diag && n == w && col > quad * 4 + r) v = -INFINITY;
                        sc[n][r] = v;
                    }
                } else {
#pragma unroll
                    for (int r = 0; r < 4; ++r) sc[n][r] = -INFINITY;
                }
            }
            // ---- online softmax (exp2 domain), per q-row ----
            float pv[4][4];
#pragma unroll
            for (int r = 0; r < 4; ++r) {
                float tm = fmaxf(fmaxf(sc[0][r], sc[1][r]), fmaxf(sc[2][r], sc[3][r]));
                tm = fmaxf(tm, __shfl_xor(tm, 1));
                tm = fmaxf(tm, __shfl_xor(tm, 2));
                tm = fmaxf(tm, __shfl_xor(tm, 4));
                tm = fmaxf(tm, __shfl_xor(tm, 8));
                float mnew  = fmaxf(mrow[r], tm);
                float alpha = exp2f(mrow[r] - mnew);
                float ps = 0.f;
#pragma unroll
                for (int n = 0; n < 4; ++n) {
                    float p = exp2f(sc[n][r] - mnew);
                    pv[n][r] = p;
                    ps += p;
                }
                ps += __shfl_xor(ps, 1);
                ps += __shfl_xor(ps, 2);
                ps += __shfl_xor(ps, 4);
                ps += __shfl_xor(ps, 8);
                lrow[r] = lrow[r] * alpha + ps;
                mrow[r] = mnew;
                O0[r] *= alpha; O1[r] *= alpha; O2[r] *= alpha; O3[r] *= alpha;
            }
            // ---- P -> LDS (C-layout -> A-layout transform) ----
#pragma unroll
            for (int n = 0; n < 4; ++n)
#pragma unroll
                for (int r = 0; r < 4; ++r)
                    Ps[w][quad * 4 + r][n * 16 + col] = f2bf(pv[n][r]);
            // ---- PV MFMAs ----
            const int ksmax = diag ? (w >> 1) : 1;
#pragma unroll
            for (int ks = 0; ks < 2; ++ks) {
                if (ks > ksmax) break;
                short8v ap  = *(const short8v*)&Ps[w][col][ks * 32 + quad * 8];
                short8v bv0 = *(const short8v*)&Vt[0  + col][ks * 32 + quad * 8];
                short8v bv1 = *(const short8v*)&Vt[16 + col][ks * 32 + quad * 8];
                short8v bv2 = *(const short8v*)&Vt[32 + col][ks * 32 + quad * 8];
                short8v bv3 = *(const short8v*)&Vt[48 + col][ks * 32 + quad * 8];
                O0 = __builtin_amdgcn_mfma_f32_16x16x32_bf16(ap, bv0, O0, 0, 0, 0);
                O1 = __builtin_amdgcn_mfma_f32_16x16x32_bf16(ap, bv1, O1, 0, 0, 0);
                O2 = __builtin_amdgcn_mfma_f32_16x16x32_bf16(ap, bv2, O2, 0, 0, 0);
                O3 = __builtin_amdgcn_mfma_f32_16x16x32_bf16(ap, bv3, O3, 0, 0, 0);
            }
        }
        // ---- epilogue: normalize + store fp32 [B][S][H*D] ----
        const int b  = bh >> 4;
        const int hh = bh & 15;
        float* orow = attn_out +
            ((size_t)(b * S_LEN) + qt * 64 + w * 16) * D_MODEL + hh * 64;
#pragma unroll
        for (int r = 0; r < 4; ++r) {
            float inv = 1.f / lrow[r];
            float* prw = orow + (size_t)(quad * 4 + r) * D_MODEL;
            prw[0  + col] = O0[r] * inv;
            prw[16 + col] = O1[r] * inv;
            prw[32 + col] = O2[r] * inv;
            prw[48 + col] = O3[r] * inv;
        }
    }
}

// ---------------------------------------------------------------------------
// Kernel 4: out = attn @ out_w^T   ([4096,1024] @ [1024,1024]^T)
// ---------------------------------------------------------------------------
__global__ __launch_bounds__(256) void gemm_proj_kernel(
    const float* __restrict__ A, const float* __restrict__ W,
    float* __restrict__ Cout) {
    int m0 = blockIdx.x * 64;
    int n0 = blockIdx.y * 64;
    int t  = threadIdx.x;
    int tx = t & 15, ty = t >> 4;

    __shared__ float As[16][68];
    __shared__ float Bs[16][68];
    float acc[4][4];
#pragma unroll
    for (int i = 0; i < 4; ++i)
#pragma unroll
        for (int jj = 0; jj < 4; ++jj) acc[i][jj] = 0.f;

    int arow = t >> 2, akq = (t & 3) << 2;
    int bn   = t >> 2, bkq = (t & 3) << 2;

    for (int kt = 0; kt < D_MODEL / 16; ++kt) {
        int k0 = kt * 16;
        float4 a4 = *(const float4*)(A + (size_t)(m0 + arow) * D_MODEL + k0 + akq);
        float4 w4 = *(const float4*)(W + (size_t)(n0 + bn) * D_MODEL + k0 + bkq);
        As[akq + 0][arow] = a4.x; As[akq + 1][arow] = a4.y;
        As[akq + 2][arow] = a4.z; As[akq + 3][arow] = a4.w;
        Bs[bkq + 0][bn] = w4.x; Bs[bkq + 1][bn] = w4.y;
        Bs[bkq + 2][bn] = w4.z; Bs[bkq + 3][bn] = w4.w;
        __syncthreads();
#pragma unroll
        for (int kk = 0; kk < 16; ++kk) {
            float4 av = *(const float4*)&As[kk][ty << 2];
            float4 bv = *(const float4*)&Bs[kk][tx << 2];
            float a_[4] = {av.x, av.y, av.z, av.w};
            float b_[4] = {bv.x, bv.y, bv.z, bv.w};
#pragma unroll
            for (int i = 0; i < 4; ++i)
#pragma unroll
                for (int jj = 0; jj < 4; ++jj) acc[i][jj] += a_[i] * b_[jj];
        }
        __syncthreads();
    }
#pragma unroll
    for (int i = 0; i < 4; ++i) {
        float4 o = make_float4(acc[i][0], acc[i][1], acc[i][2], acc[i][3]);
        *(float4*)(Cout + (size_t)(m0 + (ty << 2) + i) * D_MODEL + n0 + (tx << 2)) = o;
    }
}

// ---------------------------------------------------------------------------
extern "C" void kernel_launch(void* const* d_in, const int* in_sizes, int n_in,
                              void* d_out, int out_size, void* d_ws, size_t ws_size,
                              hipStream_t stream) {
    const float* x    = (const float*)d_in[0];
    const float* qU   = (const float*)d_in[1];
    const float* qV   = (const float*)d_in[2];
    const float* kU   = (const float*)d_in[3];
    const float* kV   = (const float*)d_in[4];
    const float* vU   = (const float*)d_in[5];
    const float* vV   = (const float*)d_in[6];
    const float* qlg  = (const float*)d_in[7];
    const float* klg  = (const float*)d_in[8];
    const float* vlg  = (const float*)d_in[9];
    const float* outw = (const float*)d_in[10];
    const int*   topk = (const int*)d_in[11];
    float* outp = (float*)d_out;

    char* ws = (char*)d_ws;
    int*   idxp = (int*)ws;                          // [3][16]
    float* wp   = (float*)(ws + 256);                // [3][16]
    float* hbuf = (float*)(ws + 512);                // [3][4096][1024] f32 = 48 MB
    short* qkvb = (short*)(ws + 512 + (size_t)3 * MROWS * D_MODEL * 4);  // bf16, 24 MB
    float* attnb = hbuf;                             // reuse h region (16 MB)

    topk_weights_kernel<<<1, 64, 0, stream>>>(qlg, klg, vlg, topk, idxp, wp);
    gemm_h_kernel<<<dim3(64, 16, 3), 256, 0, stream>>>(x, qU, kU, vU, idxp, topk, hbuf);
    gemm_qkv_kernel<<<dim3(64, 16, 3), 256, 0, stream>>>(hbuf, qV, kV, vV, idxp, wp, topk, qkvb);
    attn_mfma_kernel<<<dim3(8, 64), 256, 0, stream>>>(qkvb, attnb);
    gemm_proj_kernel<<<dim3(64, 16), 256, 0, stream>>>(attnb, outw, outp);
}

// Round 3
// 230.677 us; speedup vs baseline: 4.5248x; 1.9952x over previous
//
#include <hip/hip_runtime.h>
#include <math.h>

#define D_MODEL 1024
#define RANK    64
#define PMAX    16
#define S_LEN   1024
#define HD      64
#define MROWS   4096   // B*S
#define NHEAD   16
#define BATCH   4

typedef short short8v __attribute__((ext_vector_type(8)));
typedef float floatx4 __attribute__((ext_vector_type(4)));

typedef __attribute__((address_space(1))) const unsigned int* gptr_t;
typedef __attribute__((address_space(3))) unsigned int* lptr_t;

// async global->LDS, 16 bytes per lane (global_load_lds_dwordx4)
static __device__ __forceinline__ void async16(const void* g, void* l) {
    __builtin_amdgcn_global_load_lds((gptr_t)g, (lptr_t)l, 16, 0, 0);
}

// fp32 -> bf16 bits, round-to-nearest-even (finite inputs only)
static __device__ __forceinline__ short f2bf(float f) {
    unsigned int u = __float_as_uint(f);
    u = (u + 0x7fffu + ((u >> 16) & 1u)) >> 16;
    return (short)u;
}

// ---------------------------------------------------------------------------
// Kernel 0: softmax -> top-k -> renormalize (== softmax over selected logits)
// ---------------------------------------------------------------------------
__global__ void topk_weights_kernel(const float* __restrict__ ql,
                                    const float* __restrict__ kl,
                                    const float* __restrict__ vl,
                                    const int* __restrict__ topk,
                                    int* __restrict__ idx_out,     // [3][16]
                                    float* __restrict__ w_out) {   // [3][16]
    int bank = threadIdx.x;
    if (bank >= 3) return;
    const float* lg = (bank == 0) ? ql : (bank == 1) ? kl : vl;
    int K = *topk; if (K < 1) K = 1; if (K > PMAX) K = PMAX;
    float l[PMAX];
    for (int i = 0; i < PMAX; ++i) l[i] = lg[i];
    bool used[PMAX];
    for (int i = 0; i < PMAX; ++i) used[i] = false;
    int   sel_i[PMAX];
    float sel_l[PMAX];
    for (int j = 0; j < K; ++j) {
        int best = -1; float bv = -INFINITY;
        for (int i = 0; i < PMAX; ++i)
            if (!used[i] && l[i] > bv) { bv = l[i]; best = i; }
        used[best] = true; sel_i[j] = best; sel_l[j] = bv;
    }
    float mx = sel_l[0];
    float e[PMAX];
    float sum = 0.f;
    for (int j = 0; j < K; ++j) { e[j] = __expf(sel_l[j] - mx); sum += e[j]; }
    float inv = 1.f / sum;
    for (int j = 0; j < PMAX; ++j) {
        idx_out[bank * PMAX + j] = (j < K) ? sel_i[j] : 0;
        w_out[bank * PMAX + j]   = (j < K) ? e[j] * inv : 0.f;
    }
}

// ---------------------------------------------------------------------------
// elementwise fp32 -> bf16 (vectorized)
// ---------------------------------------------------------------------------
__global__ __launch_bounds__(256) void convert_bf16_kernel(
    const float* __restrict__ src, short* __restrict__ dst, int n4) {
    int i = blockIdx.x * 256 + threadIdx.x;
    if (i < n4) {
        float4 f = ((const float4*)src)[i];
        short4 o;
        o.x = f2bf(f.x); o.y = f2bf(f.y); o.z = f2bf(f.z); o.w = f2bf(f.w);
        ((short4*)dst)[i] = o;
    }
}

// ---------------------------------------------------------------------------
// prep: build B^T-layout bf16 bank matrices.
//  z in 0..2: Ut[bank][j*64+r][d]  = U_bank[p_j][d][r]          (1024x1024)
//  z in 3..5: Vt[bank][n][j*64+r]  = w_j * V_bank[p_j][r][n]    (1024x1024)
// ---------------------------------------------------------------------------
__global__ __launch_bounds__(256) void prep_uv_kernel(
    const float* __restrict__ qU, const float* __restrict__ kU,
    const float* __restrict__ vU,
    const float* __restrict__ qV, const float* __restrict__ kV,
    const float* __restrict__ vV,
    const int* __restrict__ idx, const float* __restrict__ wsel,
    short* __restrict__ Ut, short* __restrict__ Vt) {
    int z    = blockIdx.z;     // 0..5
    int j    = blockIdx.y;     // 0..15
    int tile = blockIdx.x;     // 0..15
    int t    = threadIdx.x;
    __shared__ float T[64][65];
    int bank = (z < 3) ? z : z - 3;
    int p = idx[bank * PMAX + j];

    if (z < 3) {
        const float* U = (bank == 0) ? qU : (bank == 1) ? kU : vU;
        const float* src = U + (size_t)p * D_MODEL * RANK;   // [d][r]
        int d0 = tile * 64;
        int rl = t & 63, dq = t >> 6;
#pragma unroll
        for (int i = 0; i < 16; ++i) {
            int dl = i * 4 + dq;
            T[rl][dl] = src[(size_t)(d0 + dl) * RANK + rl];
        }
        __syncthreads();
        short* dst = Ut + (size_t)bank * D_MODEL * D_MODEL;
        int rr = t >> 2;
#pragma unroll
        for (int i = 0; i < 4; ++i) {
            int c = (t & 3) * 16 + i * 4;
            short4 o;
            o.x = f2bf(T[rr][c + 0]); o.y = f2bf(T[rr][c + 1]);
            o.z = f2bf(T[rr][c + 2]); o.w = f2bf(T[rr][c + 3]);
            *(short4*)&dst[(size_t)(j * 64 + rr) * D_MODEL + d0 + c] = o;
        }
    } else {
        const float* V = (bank == 0) ? qV : (bank == 1) ? kV : vV;
        float wj = wsel[bank * PMAX + j];
        const float* src = V + (size_t)p * RANK * D_MODEL;    // [r][n]
        int n0 = tile * 64;
        int nl = t & 63, rq = t >> 6;
#pragma unroll
        for (int i = 0; i < 16; ++i) {
            int rl = i * 4 + rq;
            T[nl][rl] = src[(size_t)rl * D_MODEL + n0 + nl] * wj;
        }
        __syncthreads();
        short* dst = Vt + (size_t)bank * D_MODEL * D_MODEL;
        int rr = t >> 2;
#pragma unroll
        for (int i = 0; i < 4; ++i) {
            int c = (t & 3) * 16 + i * 4;
            short4 o;
            o.x = f2bf(T[rr][c + 0]); o.y = f2bf(T[rr][c + 1]);
            o.z = f2bf(T[rr][c + 2]); o.w = f2bf(T[rr][c + 3]);
            *(short4*)&dst[(size_t)(n0 + rr) * D_MODEL + j * 64 + c] = o;
        }
    }
}

// ---------------------------------------------------------------------------
// m97-style bf16 MFMA GEMM tile body: C[128x128] += A[128xkl] * B^T[128xkl]
// A: [m][k] stride 1024 bf16; B: [n][k] stride 1024 bf16. 256 thr = 4 waves,
// wave (wm,wn) owns 64x64; per 32-k step: 8 ds_read_b128 + 16 MFMA.
// ---------------------------------------------------------------------------
static __device__ __forceinline__ void mfma_gemm_tile(
    const short* __restrict__ A, const short* __restrict__ B, int kl,
    int m0, int n0, short* As, short* Bs, floatx4 acc[4][4]) {
    const int t    = threadIdx.x;
    const int w    = t >> 6;
    const int lane = t & 63;
    const int wm   = w & 1, wn = w >> 1;
    const int colL = lane & 15, quad = lane >> 4;
    const int srow  = lane >> 2;        // 0..15
    const int skoff = (lane & 3) * 8;   // 8-short (16B) chunk

#pragma unroll
    for (int i = 0; i < 4; ++i)
#pragma unroll
        for (int j = 0; j < 4; ++j) acc[i][j] = (floatx4){0.f, 0.f, 0.f, 0.f};

    for (int k0 = 0; k0 < kl; k0 += 32) {
        async16(A + (size_t)(m0 + w * 16 + srow) * D_MODEL + k0 + skoff,
                As + (w * 16 + srow) * 32 + skoff);
        async16(A + (size_t)(m0 + 64 + w * 16 + srow) * D_MODEL + k0 + skoff,
                As + (64 + w * 16 + srow) * 32 + skoff);
        async16(B + (size_t)(n0 + w * 16 + srow) * D_MODEL + k0 + skoff,
                Bs + (w * 16 + srow) * 32 + skoff);
        async16(B + (size_t)(n0 + 64 + w * 16 + srow) * D_MODEL + k0 + skoff,
                Bs + (64 + w * 16 + srow) * 32 + skoff);
        __syncthreads();
        short8v af[4], bf[4];
#pragma unroll
        for (int i = 0; i < 4; ++i)
            af[i] = *(const short8v*)&As[(wm * 64 + i * 16 + colL) * 32 + quad * 8];
#pragma unroll
        for (int j = 0; j < 4; ++j)
            bf[j] = *(const short8v*)&Bs[(wn * 64 + j * 16 + colL) * 32 + quad * 8];
#pragma unroll
        for (int i = 0; i < 4; ++i)
#pragma unroll
            for (int j = 0; j < 4; ++j)
                acc[i][j] = __builtin_amdgcn_mfma_f32_16x16x32_bf16(af[i], bf[j], acc[i][j], 0, 0, 0);
        __syncthreads();
    }
}

// ---------------------------------------------------------------------------
// Kernel 1: h[bank] = xb @ Ut[bank]^T  -> bf16 [3][4096][1024] (K*64 cols)
// ---------------------------------------------------------------------------
__global__ __launch_bounds__(256) void gemm_h_kernel(
    const short* __restrict__ xb, const short* __restrict__ Ut,
    const int* __restrict__ topk, short* __restrict__ h) {
    int K = *topk; if (K < 1) K = 1; if (K > PMAX) K = PMAX;
    int n0 = blockIdx.y * 128;
    if (n0 >= K * 64) return;
    int m0 = blockIdx.x * 128;
    int bank = blockIdx.z;
    __shared__ short As[128 * 32];
    __shared__ short Bs[128 * 32];
    floatx4 acc[4][4];
    mfma_gemm_tile(xb, Ut + (size_t)bank * D_MODEL * D_MODEL, D_MODEL, m0, n0, As, Bs, acc);

    const int t = threadIdx.x, w = t >> 6, lane = t & 63;
    const int wm = w & 1, wn = w >> 1, colL = lane & 15, quad = lane >> 4;
    short* H = h + (size_t)bank * MROWS * D_MODEL;
#pragma unroll
    for (int i = 0; i < 4; ++i)
#pragma unroll
        for (int j = 0; j < 4; ++j)
#pragma unroll
            for (int r = 0; r < 4; ++r)
                H[(size_t)(m0 + wm * 64 + i * 16 + quad * 4 + r) * D_MODEL +
                  (n0 + wn * 64 + j * 16 + colL)] = f2bf(acc[i][j][r]);
}

// ---------------------------------------------------------------------------
// Kernel 2: qkv[bank] = h[bank] @ Vt[bank]^T -> bf16 [3][B*H][S][D]
// ---------------------------------------------------------------------------
__global__ __launch_bounds__(256) void gemm_qkv_kernel(
    const short* __restrict__ h, const short* __restrict__ Vt,
    const int* __restrict__ topk, short* __restrict__ qkv) {
    int K = *topk; if (K < 1) K = 1; if (K > PMAX) K = PMAX;
    int m0 = blockIdx.x * 128;
    int n0 = blockIdx.y * 128;
    int bank = blockIdx.z;
    __shared__ short As[128 * 32];
    __shared__ short Bs[128 * 32];
    floatx4 acc[4][4];
    mfma_gemm_tile(h + (size_t)bank * MROWS * D_MODEL,
                   Vt + (size_t)bank * D_MODEL * D_MODEL, K * 64, m0, n0, As, Bs, acc);

    const int t = threadIdx.x, w = t >> 6, lane = t & 63;
    const int wm = w & 1, wn = w >> 1, colL = lane & 15, quad = lane >> 4;
    short* outp = qkv + (size_t)bank * MROWS * D_MODEL;
#pragma unroll
    for (int i = 0; i < 4; ++i)
#pragma unroll
        for (int j = 0; j < 4; ++j)
#pragma unroll
            for (int r = 0; r < 4; ++r) {
                int m = m0 + wm * 64 + i * 16 + quad * 4 + r;
                int n = n0 + wn * 64 + j * 16 + colL;
                int b = m >> 10, s = m & 1023;
                int head = n >> 6, d = n & 63;
                outp[(((size_t)(b * NHEAD + head) << 10) + s) * HD + d] = f2bf(acc[i][j][r]);
            }
}

// ---------------------------------------------------------------------------
// Kernel 4: out = attn(bf16) @ out_w(bf16)^T -> fp32 d_out
// ---------------------------------------------------------------------------
__global__ __launch_bounds__(256) void gemm_proj_kernel(
    const short* __restrict__ attnb, const short* __restrict__ wb,
    float* __restrict__ outp) {
    int m0 = blockIdx.x * 128;
    int n0 = blockIdx.y * 128;
    __shared__ short As[128 * 32];
    __shared__ short Bs[128 * 32];
    floatx4 acc[4][4];
    mfma_gemm_tile(attnb, wb, D_MODEL, m0, n0, As, Bs, acc);

    const int t = threadIdx.x, w = t >> 6, lane = t & 63;
    const int wm = w & 1, wn = w >> 1, colL = lane & 15, quad = lane >> 4;
#pragma unroll
    for (int i = 0; i < 4; ++i)
#pragma unroll
        for (int j = 0; j < 4; ++j)
#pragma unroll
            for (int r = 0; r < 4; ++r)
                outp[(size_t)(m0 + wm * 64 + i * 16 + quad * 4 + r) * D_MODEL +
                     (n0 + wn * 64 + j * 16 + colL)] = acc[i][j][r];
}

// ---------------------------------------------------------------------------
// Kernel 3: causal flash attention, bf16 MFMA (16x16x32). Output bf16.
// ---------------------------------------------------------------------------
__global__ __launch_bounds__(256) void attn_mfma_kernel(
    const short* __restrict__ qkv,    // bf16 [3][BH=64][S=1024][D=64]
    short* __restrict__ attn_out) {   // bf16 [B=4][S=1024][H*D=1024]
    const int t    = threadIdx.x;
    const int w    = t >> 6;
    const int lane = t & 63;
    const int col  = lane & 15;
    const int quad = lane >> 4;
    const int pr   = blockIdx.x;   // 0..7
    const int bh   = blockIdx.y;   // 0..63
    const size_t HS   = (size_t)S_LEN * HD;
    const size_t BSTR = (size_t)MROWS * D_MODEL;
    const short* Qg = qkv + (size_t)bh * HS;
    const short* Kg = qkv + BSTR + (size_t)bh * HS;
    const short* Vg = qkv + 2 * BSTR + (size_t)bh * HS;

    __shared__ short Ks[64][72];      // [key][d]
    __shared__ short Vt[64][72];      // [d][key] (transposed)
    __shared__ short Ps[4][16][72];   // per-wave P [q][key]

    const float SC = 0.125f * 1.44269504f;   // 1/sqrt(64) * log2(e)

    for (int ph = 0; ph < 2; ++ph) {
        const int qt = ph ? (15 - pr) : pr;
        const int qrow = qt * 64 + w * 16 + col;
        short8v aq0 = *(const short8v*)(Qg + (size_t)qrow * HD + quad * 8);
        short8v aq1 = *(const short8v*)(Qg + (size_t)qrow * HD + 32 + quad * 8);
        floatx4 O0 = {0.f, 0.f, 0.f, 0.f}, O1 = O0, O2 = O0, O3 = O0;
        float mrow[4] = {-INFINITY, -INFINITY, -INFINITY, -INFINITY};
        float lrow[4] = {0.f, 0.f, 0.f, 0.f};

        for (int jt = 0; jt <= qt; ++jt) {
            __syncthreads();
            // ---- stage K tile (row-major) ----
            {
                int c = t;
                int key = c >> 3, db = (c & 7) * 8;
                *(short8v*)&Ks[key][db] =
                    *(const short8v*)(Kg + (size_t)(jt * 64 + key) * HD + db);
                c = t + 256;
                key = c >> 3; db = (c & 7) * 8;
                *(short8v*)&Ks[key][db] =
                    *(const short8v*)(Kg + (size_t)(jt * 64 + key) * HD + db);
            }
            // ---- stage V tile transposed (packed pair writes) ----
            {
                int k0 = (t & 31) * 2;
                int db = (t >> 5) * 8;
                short8v v0 = *(const short8v*)(Vg + (size_t)(jt * 64 + k0) * HD + db);
                short8v v1 = *(const short8v*)(Vg + (size_t)(jt * 64 + k0 + 1) * HD + db);
#pragma unroll
                for (int i = 0; i < 8; ++i) {
                    unsigned int pk = (unsigned int)(unsigned short)v0[i] |
                                      ((unsigned int)(unsigned short)v1[i] << 16);
                    *(unsigned int*)&Vt[db + i][k0] = pk;
                }
            }
            __syncthreads();

            const bool diag = (jt == qt);
            const int  nmax = diag ? w : 3;
            float sc[4][4];
#pragma unroll
            for (int n = 0; n < 4; ++n) {
                if (n <= nmax) {
                    floatx4 c4 = {0.f, 0.f, 0.f, 0.f};
                    short8v b0 = *(const short8v*)&Ks[n * 16 + col][quad * 8];
                    short8v b1 = *(const short8v*)&Ks[n * 16 + col][32 + quad * 8];
                    c4 = __builtin_amdgcn_mfma_f32_16x16x32_bf16(aq0, b0, c4, 0, 0, 0);
                    c4 = __builtin_amdgcn_mfma_f32_16x16x32_bf16(aq1, b1, c4, 0, 0, 0);
#pragma unroll
                    for (int r = 0; r < 4; ++r) {
                        float v = c4[r] * SC;
                        if (diag && n == w && col > quad * 4 + r) v = -INFINITY;
                        sc[n][r] = v;
                    }
                } else {
#pragma unroll
                    for (int r = 0; r < 4; ++r) sc[n][r] = -INFINITY;
                }
            }
            // ---- online softmax (exp2 domain), per q-row ----
            float pv[4][4];
#pragma unroll
            for (int r = 0; r < 4; ++r) {
                float tm = fmaxf(fmaxf(sc[0][r], sc[1][r]), fmaxf(sc[2][r], sc[3][r]));
                tm = fmaxf(tm, __shfl_xor(tm, 1));
                tm = fmaxf(tm, __shfl_xor(tm, 2));
                tm = fmaxf(tm, __shfl_xor(tm, 4));
                tm = fmaxf(tm, __shfl_xor(tm, 8));
                float mnew  = fmaxf(mrow[r], tm);
                float alpha = exp2f(mrow[r] - mnew);
                float ps = 0.f;
#pragma unroll
                for (int n = 0; n < 4; ++n) {
                    float p = exp2f(sc[n][r] - mnew);
                    pv[n][r] = p;
                    ps += p;
                }
                ps += __shfl_xor(ps, 1);
                ps += __shfl_xor(ps, 2);
                ps += __shfl_xor(ps, 4);
                ps += __shfl_xor(ps, 8);
                lrow[r] = lrow[r] * alpha + ps;
                mrow[r] = mnew;
                O0[r] *= alpha; O1[r] *= alpha; O2[r] *= alpha; O3[r] *= alpha;
            }
            // ---- P -> LDS (C-layout -> A-layout transform) ----
#pragma unroll
            for (int n = 0; n < 4; ++n)
#pragma unroll
                for (int r = 0; r < 4; ++r)
                    Ps[w][quad * 4 + r][n * 16 + col] = f2bf(pv[n][r]);
            // ---- PV MFMAs ----
            const int ksmax = diag ? (w >> 1) : 1;
#pragma unroll
            for (int ks = 0; ks < 2; ++ks) {
                if (ks > ksmax) break;
                short8v ap  = *(const short8v*)&Ps[w][col][ks * 32 + quad * 8];
                short8v bv0 = *(const short8v*)&Vt[0  + col][ks * 32 + quad * 8];
                short8v bv1 = *(const short8v*)&Vt[16 + col][ks * 32 + quad * 8];
                short8v bv2 = *(const short8v*)&Vt[32 + col][ks * 32 + quad * 8];
                short8v bv3 = *(const short8v*)&Vt[48 + col][ks * 32 + quad * 8];
                O0 = __builtin_amdgcn_mfma_f32_16x16x32_bf16(ap, bv0, O0, 0, 0, 0);
                O1 = __builtin_amdgcn_mfma_f32_16x16x32_bf16(ap, bv1, O1, 0, 0, 0);
                O2 = __builtin_amdgcn_mfma_f32_16x16x32_bf16(ap, bv2, O2, 0, 0, 0);
                O3 = __builtin_amdgcn_mfma_f32_16x16x32_bf16(ap, bv3, O3, 0, 0, 0);
            }
        }
        // ---- epilogue: normalize + store bf16 [B][S][H*D] ----
        const int b  = bh >> 4;
        const int hh = bh & 15;
        short* orow = attn_out +
            ((size_t)(b * S_LEN) + qt * 64 + w * 16) * D_MODEL + hh * 64;
#pragma unroll
        for (int r = 0; r < 4; ++r) {
            float inv = 1.f / lrow[r];
            short* prw = orow + (size_t)(quad * 4 + r) * D_MODEL;
            prw[0  + col] = f2bf(O0[r] * inv);
            prw[16 + col] = f2bf(O1[r] * inv);
            prw[32 + col] = f2bf(O2[r] * inv);
            prw[48 + col] = f2bf(O3[r] * inv);
        }
    }
}

// ---------------------------------------------------------------------------
extern "C" void kernel_launch(void* const* d_in, const int* in_sizes, int n_in,
                              void* d_out, int out_size, void* d_ws, size_t ws_size,
                              hipStream_t stream) {
    const float* x    = (const float*)d_in[0];
    const float* qU   = (const float*)d_in[1];
    const float* qV   = (const float*)d_in[2];
    const float* kU   = (const float*)d_in[3];
    const float* kV   = (const float*)d_in[4];
    const float* vU   = (const float*)d_in[5];
    const float* vV   = (const float*)d_in[6];
    const float* qlg  = (const float*)d_in[7];
    const float* klg  = (const float*)d_in[8];
    const float* vlg  = (const float*)d_in[9];
    const float* outw = (const float*)d_in[10];
    const int*   topk = (const int*)d_in[11];
    float* outp = (float*)d_out;

    char* ws = (char*)d_ws;
    int*   idxp = (int*)ws;                              // [3][16]
    float* wp   = (float*)(ws + 256);                    // [3][16]
    short* xb   = (short*)(ws + 512);                    // 8 MB
    short* Ut   = xb + (size_t)MROWS * D_MODEL;          // 6 MB
    short* Vt   = Ut + (size_t)3 * D_MODEL * D_MODEL;    // 6 MB
    short* wb   = Vt + (size_t)3 * D_MODEL * D_MODEL;    // 2 MB
    short* hbuf = wb + (size_t)D_MODEL * D_MODEL;        // 24 MB
    short* qkvb = hbuf + (size_t)3 * MROWS * D_MODEL;    // 24 MB
    short* attnb = qkvb + (size_t)3 * MROWS * D_MODEL;   // 8 MB

    topk_weights_kernel<<<1, 64, 0, stream>>>(qlg, klg, vlg, topk, idxp, wp);
    convert_bf16_kernel<<<(MROWS * D_MODEL / 4 + 255) / 256, 256, 0, stream>>>(
        x, xb, MROWS * D_MODEL / 4);
    convert_bf16_kernel<<<(D_MODEL * D_MODEL / 4 + 255) / 256, 256, 0, stream>>>(
        outw, wb, D_MODEL * D_MODEL / 4);
    prep_uv_kernel<<<dim3(16, 16, 6), 256, 0, stream>>>(
        qU, kU, vU, qV, kV, vV, idxp, wp, Ut, Vt);
    gemm_h_kernel<<<dim3(32, 8, 3), 256, 0, stream>>>(xb, Ut, topk, hbuf);
    gemm_qkv_kernel<<<dim3(32, 8, 3), 256, 0, stream>>>(hbuf, Vt, topk, qkvb);
    attn_mfma_kernel<<<dim3(8, 64), 256, 0, stream>>>(qkvb, attnb);
    gemm_proj_kernel<<<dim3(32, 8), 256, 0, stream>>>(attnb, wb, outp);
}